// Round 1
// 209.427 us; speedup vs baseline: 1.0664x; 1.0664x over previous
//
#include <hip/hip_runtime.h>
#include <cstdint>
#include <cstddef>

// Problem constants
#define B_SZ   64
#define IN_CH  32
#define OUT_CH 32
#define NMAPS  64
#define HW     4096          // 64*64
#define CTRLN  512
#define NROWS  4160          // NF(64) + NI(2048) + NO(2048)
#define OUT0_SZ (B_SZ*OUT_CH*HW)
#define TILE   128

typedef short bf8_t  __attribute__((ext_vector_type(8)));   // 8 bf16 = 4 VGPR
typedef short bf4_t  __attribute__((ext_vector_type(4)));   // 4 bf16 = 2 VGPR
typedef float f32x4  __attribute__((ext_vector_type(4)));

__device__ __forceinline__ unsigned short f2bf(float f) {
    union { float f; uint32_t u; } v; v.f = f;
    return (unsigned short)((v.u + 0x7FFFu + ((v.u >> 16) & 1u)) >> 16);  // RNE
}
__device__ __forceinline__ float bf2f(unsigned short h) {
    union { uint32_t u; float f; } v; v.u = (uint32_t)h << 16;
    return v.f;
}
__device__ __forceinline__ float fast_tanh(float x) {
    float e = __expf(2.0f * x);               // tanh = 1 - 2/(e^{2x}+1)
    return 1.0f - 2.0f * __builtin_amdgcn_rcpf(e + 1.0f);
}

// ---------------------------------------------------------------------------
// Kernel 1: ctrl = controls @ W^T via split-bf16 MFMA.
// Each fp32 operand is split x = hi + lo (bf16 each); C = Ahh + Ahl + Alh
// (the ll term is ~2^-18 relative -> dropped) gives ~fp32 accuracy at
// 3 MFMAs per k-step.  No LDS, no barriers, no smem/LDS lgkmcnt coupling:
// both A (W row-major) and B (controls row-major) fragments are
// k-contiguous straight from global; hi/lo split happens in VGPRs.
// Tile: D[j][b] 16x16, M=j (W rows), N=b (batch).
// Grid: 260 blocks x 4 waves; wave w owns batch sub-tile [16w,16w+16).
// ---------------------------------------------------------------------------
__global__ __launch_bounds__(256) void ctrl_gemm(
    const float* __restrict__ controls, const float* __restrict__ W,
    float* __restrict__ ws)
{
    const int tid  = threadIdx.x;
    const int l    = tid & 63;
    const int w    = __builtin_amdgcn_readfirstlane(tid >> 6);
    const int quad = l >> 4;
    const int mlo  = l & 15;
    const int j0   = blockIdx.x * 16;

    const float* wr = W + (size_t)(j0 + mlo) * CTRLN;            // A row (j)
    const float* cr = controls + (size_t)(w * 16 + mlo) * CTRLN; // B row (b)

    f32x4 acc = {0.f, 0.f, 0.f, 0.f};
#pragma unroll 4
    for (int ks = 0; ks < 16; ++ks) {
        const int k0 = ks * 32 + quad * 8;
        const float4 a0 = *(const float4*)(wr + k0);
        const float4 a1 = *(const float4*)(wr + k0 + 4);
        const float4 b0 = *(const float4*)(cr + k0);
        const float4 b1 = *(const float4*)(cr + k0 + 4);
        const float av[8] = {a0.x,a0.y,a0.z,a0.w,a1.x,a1.y,a1.z,a1.w};
        const float bv[8] = {b0.x,b0.y,b0.z,b0.w,b1.x,b1.y,b1.z,b1.w};
        bf8_t ah, al_, bh, bl;
#pragma unroll
        for (int e = 0; e < 8; ++e) {
            const unsigned short hA = f2bf(av[e]);
            ah[e]  = (short)hA;
            al_[e] = (short)f2bf(av[e] - bf2f(hA));
            const unsigned short hB = f2bf(bv[e]);
            bh[e]  = (short)hB;
            bl[e]  = (short)f2bf(bv[e] - bf2f(hB));
        }
        acc = __builtin_amdgcn_mfma_f32_16x16x32_bf16(ah,  bh, acc, 0, 0, 0);
        acc = __builtin_amdgcn_mfma_f32_16x16x32_bf16(ah,  bl, acc, 0, 0, 0);
        acc = __builtin_amdgcn_mfma_f32_16x16x32_bf16(al_, bh, acc, 0, 0, 0);
    }

    // D layout: col = lane&15 -> batch, row = quad*4+reg -> j (4 consecutive)
    const int bidx = w * 16 + mlo;
    float4 r;
    r.x = acc[0]; r.y = acc[1]; r.z = acc[2]; r.w = acc[3];
    *(float4*)(ws + (size_t)bidx * NROWS + j0 + quad * 4) = r;
}

// ---------------------------------------------------------------------------
// Kernel 2: MFMA fused kernel, OUTPUT-TRANSPOSED tiling: D[p][m].
// Latency-targeted restructure of the 65 us version:
//  - X A-fragments built DIRECTLY from global (zero cross-lane reuse ->
//    the old LDS transpose staging was pure overhead + its b16 writes were
//    the main bank-conflict source + it put 16 KB of HBM latency in front
//    of the barrier).
//  - state prefetched into VGPRs at kernel top: its ~900-cycle HBM latency
//    hides under gate staging + phase A instead of sitting on the epilogue
//    critical path.
//  - LDS overlay: Tt reuses the IGs bytes once bg-fragments are in regs
//    (one extra cheap barrier).  38.9 KB -> 23.3 KB => 5 blocks/CU
//    (VGPR-capped at 102 via __launch_bounds__(256,5)); LDS alone allows 6.
// ---------------------------------------------------------------------------
__global__ __launch_bounds__(256, 5) void vstm_main(
    const float* __restrict__ inputs, const float* __restrict__ state,
    const float* __restrict__ ws, float* __restrict__ out)
{
    __shared__ __align__(16) unsigned char smem[23296];
    unsigned short* const IGs = (unsigned short*)(smem);          // [64][40], phase A
    unsigned short* const Tt  = (unsigned short*)(smem);          // [128][72], overlays IGs
    unsigned short* const OGs = (unsigned short*)(smem + 18432);  // [32][72], persistent
    float*          const fs  = (float*)(smem + 23040);           // [64],     persistent

    const int tid  = threadIdx.x;
    const int b    = blockIdx.y;
    const int tile = blockIdx.x * TILE;
    const int w    = __builtin_amdgcn_readfirstlane(tid >> 6);
    const int l    = tid & 63;
    const int quad = l >> 4;
    const int mlo  = l & 15;

    // ---- issue gate loads first (they gate barrier 1) ----
    const float* g = ws + (size_t)b * NROWS;
    const float fsv = g[tid & 63];
    float4 giv[2], gov[2];
#pragma unroll
    for (int i = 0; i < 2; ++i) {
        const int e = (i * 256 + tid) * 4;                   // 0..2044
        giv[i] = *(const float4*)(g + 64 + e);               // ig[m*32+c]
        gov[i] = *(const float4*)(g + 2112 + e);             // og[o*64+m]
    }

    // ---- issue X fragment loads (direct from global, coalesced b32:
    //      fixed (pc,j): 16 consecutive p across mlo, 4 c-rows across quad) ----
    const float* xb = inputs + (size_t)b * IN_CH * HW + tile + w * 32;
    float xf[2][8];
#pragma unroll
    for (int pc = 0; pc < 2; ++pc)
#pragma unroll
        for (int j = 0; j < 8; ++j)
            xf[pc][j] = xb[(size_t)(quad * 8 + j) * HW + pc * 16 + mlo];

    // ---- issue state prefetch (consumed in epilogue) ----
    const float* stb = state + (size_t)b * NMAPS * HW + tile;
    float4 stv[4][2];
#pragma unroll
    for (int mc = 0; mc < 4; ++mc)
#pragma unroll
        for (int pc = 0; pc < 2; ++pc)
            stv[mc][pc] = *(const float4*)(stb + (size_t)(mc * 16 + mlo) * HW
                                           + w * 32 + pc * 16 + quad * 4);

    // ---- stage gates to LDS ----
    if (tid < 64) fs[tid] = fsv;
#pragma unroll
    for (int i = 0; i < 2; ++i) {
        const int e = (i * 256 + tid) * 4;
        bf4_t vi = { (short)f2bf(giv[i].x), (short)f2bf(giv[i].y),
                     (short)f2bf(giv[i].z), (short)f2bf(giv[i].w) };
        *(bf4_t*)&IGs[(e >> 5) * 40 + (e & 31)] = vi;
        bf4_t vo = { (short)f2bf(gov[i].x), (short)f2bf(gov[i].y),
                     (short)f2bf(gov[i].z), (short)f2bf(gov[i].w) };
        *(bf4_t*)&OGs[(e >> 6) * 72 + (e & 63)] = vo;
    }
    __syncthreads();                        // barrier 1: gates staged

    // ---- B-fragments (IG) from LDS ----
    bf8_t bg[4];
#pragma unroll
    for (int mc = 0; mc < 4; ++mc)
        bg[mc] = *(const bf8_t*)&IGs[(mc * 16 + mlo) * 40 + quad * 8];

    // ---- A-fragments from xf (register-only conversion) ----
    bf8_t af[2];
#pragma unroll
    for (int pc = 0; pc < 2; ++pc)
#pragma unroll
        for (int j = 0; j < 8; ++j)
            af[pc][j] = (short)f2bf(xf[pc][j]);

    __syncthreads();                        // barrier 2: IGs consumed -> Tt may overwrite

    // ---- Phase A: D[p][m], wave w owns p in [32w, 32w+32) ----
    f32x4 acc[2][4];
#pragma unroll
    for (int pc = 0; pc < 2; ++pc)
#pragma unroll
        for (int mc = 0; mc < 4; ++mc) {
            acc[pc][mc] = (f32x4){0.f, 0.f, 0.f, 0.f};
            acc[pc][mc] = __builtin_amdgcn_mfma_f32_16x16x32_bf16(
                af[pc], bg[mc], acc[pc][mc], 0, 0, 0);
        }

    // ---- epilogue: ns = acc + state*f (state already in regs), float4 I/O,
    //      tanh -> Tt[p][m] bf16 (wave-private rows) ----
    float* nsb = out + OUT0_SZ + (size_t)b * NMAPS * HW + tile;
#pragma unroll
    for (int mc = 0; mc < 4; ++mc) {
        const int m = mc * 16 + mlo;
        const float fgt = fs[m];
#pragma unroll
        for (int pc = 0; pc < 2; ++pc) {
            const int p0 = w * 32 + pc * 16 + quad * 4;
            const float4 st = stv[mc][pc];
            float4 ns;
            ns.x = acc[pc][mc][0] + st.x * fgt;
            ns.y = acc[pc][mc][1] + st.y * fgt;
            ns.z = acc[pc][mc][2] + st.z * fgt;
            ns.w = acc[pc][mc][3] + st.w * fgt;
            *(float4*)(nsb + (size_t)m * HW + p0) = ns;
            Tt[(p0 + 0) * 72 + m] = f2bf(fast_tanh(ns.x));
            Tt[(p0 + 1) * 72 + m] = f2bf(fast_tanh(ns.y));
            Tt[(p0 + 2) * 72 + m] = f2bf(fast_tanh(ns.z));
            Tt[(p0 + 3) * 72 + m] = f2bf(fast_tanh(ns.w));
        }
    }
    // no barrier: wave w reads only Tt rows it wrote

    // ---- Phase B: D[p][o] = T^T[p][m] x OG^T[m][o], K=64 -> 2 steps ----
    bf8_t ag[2][2], at[2][2];
#pragma unroll
    for (int oc = 0; oc < 2; ++oc)
#pragma unroll
        for (int ks = 0; ks < 2; ++ks)
            ag[oc][ks] = *(const bf8_t*)&OGs[(oc * 16 + mlo) * 72 + ks * 32 + quad * 8];
#pragma unroll
    for (int pc = 0; pc < 2; ++pc)
#pragma unroll
        for (int ks = 0; ks < 2; ++ks)
            at[pc][ks] = *(const bf8_t*)&Tt[(w * 32 + pc * 16 + mlo) * 72 + ks * 32 + quad * 8];

    f32x4 acc2[2][2];
#pragma unroll
    for (int pc = 0; pc < 2; ++pc)
#pragma unroll
        for (int oc = 0; oc < 2; ++oc) {
            acc2[pc][oc] = (f32x4){0.f, 0.f, 0.f, 0.f};
#pragma unroll
            for (int ks = 0; ks < 2; ++ks)
                acc2[pc][oc] = __builtin_amdgcn_mfma_f32_16x16x32_bf16(
                    at[pc][ks], ag[oc][ks], acc2[pc][oc], 0, 0, 0);
        }

    float* ob = out + (size_t)b * OUT_CH * HW + tile;
#pragma unroll
    for (int pc = 0; pc < 2; ++pc)
#pragma unroll
        for (int oc = 0; oc < 2; ++oc) {
            const int p0 = w * 32 + pc * 16 + quad * 4;
            const int o  = oc * 16 + mlo;
            float4 r;
            r.x = acc2[pc][oc][0];
            r.y = acc2[pc][oc][1];
            r.z = acc2[pc][oc][2];
            r.w = acc2[pc][oc][3];
            *(float4*)(ob + (size_t)o * HW + p0) = r;
        }
}

extern "C" void kernel_launch(void* const* d_in, const int* in_sizes, int n_in,
                              void* d_out, int out_size, void* d_ws, size_t ws_size,
                              hipStream_t stream) {
    const float* inputs   = (const float*)d_in[0];
    const float* state    = (const float*)d_in[1];
    const float* controls = (const float*)d_in[2];
    const float* W        = (const float*)d_in[3];
    float*       out      = (float*)d_out;
    float*       ws       = (float*)d_ws;

    ctrl_gemm<<<dim3(NROWS / 16), 256, 0, stream>>>(controls, W, ws);

    dim3 g2(HW / TILE, B_SZ);
    vstm_main<<<g2, 256, 0, stream>>>(inputs, state, ws, out);
}